// Round 1
// 1314.829 us; speedup vs baseline: 2.7481x; 2.7481x over previous
//
#include <hip/hip_runtime.h>
#include <hip/hip_bf16.h>
#include <math.h>

// CrissCrossAttention (height branch), B=8 H=128 W=128 C=512, fp32 in/out.
//
// MFMA rewrite. Algebra: energy = x (Wq^T Wk) x^T per (b,w) column;
// out = gamma*(attn @ (x Wv^T)) + x.
//   K0:  MT = (Wq^T Wk)^T split into bf16 hi/lo (ws: 1 MB).
//   K1:  per-column fused kernel, all GEMMs on v_mfma_f32_16x16x32_bf16.
//        Logit path (T = x@M, E = T@x^T) uses Dekker hi/lo bf16 splits with
//        3 MFMA passes (hh+hl+lh) -> fp32-quality logits (lo*lo ~ 2^-16 rel).
//        Value path (V = x@Wv^T, O = attn@V) single bf16 (error not
//        softmax-amplified; matches previous kernel's bf16 tiles).
// Fragment loads use a SINGLE contiguous ds_read_b128 per frag (k = 8*(l>>4)+j
// convention). Any k-permutation applied identically to A and B frags leaves
// the MFMA dot product invariant, so this is correct regardless of the HW's
// exact per-lane k order. C/D layout = HW-verified: col=lane&15, row=4*(l>>4)+r.
// LDS tiles unpadded with XOR swizzle byte^=((row&7)<<4) -> <=2-way conflicts.
// Arena phase-unioned to exactly 64 KB static -> 2 blocks/CU.

#define HH 128
#define WW 128
#define CS 512
#define HSTRIDE 65536  // WW*CS

typedef __attribute__((ext_vector_type(8))) short bf16x8;  // one A/B fragment (4 VGPR)
typedef __attribute__((ext_vector_type(4))) short s4v;
typedef __attribute__((ext_vector_type(4))) float f32x4;

__device__ __forceinline__ short f2bf(float f) {
  __hip_bfloat16 h = __float2bfloat16(f);
  short s;
  __builtin_memcpy(&s, &h, 2);
  return s;
}
__device__ __forceinline__ float bf2f(short s) {
  __hip_bfloat16 h;
  __builtin_memcpy(&h, &s, 2);
  return __bfloat162float(h);
}
__device__ __forceinline__ f32x4 MFMA(bf16x8 a, bf16x8 b, f32x4 c) {
  return __builtin_amdgcn_mfma_f32_16x16x32_bf16(a, b, c, 0, 0, 0);
}

// ---- swizzled LDS tiles ----
// frag64 : [rows][64] bf16 tile (128 B rows); frag128: [rows][128] bf16 (256 B rows).
// byte-in-row XOR ((row&7)<<4) spreads the 16-B slots of 16 consecutive rows
// over 8 slots (2 lanes/slot = free 2-way), killing the stride=0(mod 128B)
// 16-way conflict. Same XOR applied on write and read (both-sides rule).
__device__ __forceinline__ bf16x8 frag64(const char* base, int row, int ks, int lq) {
  int byte = (row << 7) + (((ks << 6) + (lq << 4)) ^ ((row & 7) << 4));
  return *(const bf16x8*)(base + byte);
}
__device__ __forceinline__ bf16x8 frag128(const char* base, int row, int ks, int lq) {
  int byte = (row << 8) + (((ks << 6) + (lq << 4)) ^ ((row & 7) << 4));
  return *(const bf16x8*)(base + byte);
}
__device__ __forceinline__ void st64(char* base, int row, int ebase, s4v v) {
  int byte = (row << 7) + ((ebase << 1) ^ ((row & 7) << 4));
  *(s4v*)(base + byte) = v;
}
__device__ __forceinline__ void st128(char* base, int row, int ebase, s4v v) {
  int byte = (row << 8) + ((ebase << 1) ^ ((row & 7) << 4));
  *(s4v*)(base + byte) = v;
}

// stage a [128][64] f32 window (global row stride rs) as swizzled bf16 hi/lo tiles
__device__ __forceinline__ void stage_hilo(const float* __restrict__ src, size_t rs,
                                           char* hi, char* lo, int tid) {
#pragma unroll
  for (int s = 0; s < 8; ++s) {
    int idx = tid + 256 * s;
    int row = idx >> 4;
    int e0 = (idx & 15) << 2;
    const float4 v = *(const float4*)(src + (size_t)row * rs + e0);
    s4v h, l;
#pragma unroll
    for (int r = 0; r < 4; ++r) {
      float f = ((const float*)&v)[r];
      short hb = f2bf(f);
      h[r] = hb;
      l[r] = f2bf(f - bf2f(hb));  // exact (Sterbenz): residual of RNE bf16 round
    }
    st64(hi, row, e0, h);
    st64(lo, row, e0, l);
  }
}
__device__ __forceinline__ void stage_hi(const float* __restrict__ src, size_t rs,
                                         char* hi, int tid) {
#pragma unroll
  for (int s = 0; s < 8; ++s) {
    int idx = tid + 256 * s;
    int row = idx >> 4;
    int e0 = (idx & 15) << 2;
    const float4 v = *(const float4*)(src + (size_t)row * rs + e0);
    s4v h;
#pragma unroll
    for (int r = 0; r < 4; ++r) h[r] = f2bf(((const float*)&v)[r]);
    st64(hi, row, e0, h);
  }
}
// stage a [64][64] bf16 window of MT (global row stride 512) into a swizzled tile
__device__ __forceinline__ void stage_mt(const short* __restrict__ src, char* dst, int tid) {
#pragma unroll
  for (int s = 0; s < 4; ++s) {
    int idx = tid + 256 * s;
    int row = idx >> 4;
    int e0 = (idx & 15) << 2;
    s4v v = *(const s4v*)(src + (size_t)row * 512 + e0);
    st64(dst, row, e0, v);
  }
}

// K0: MT[j][i] = M[i][j] = sum_a Wq[a][i]*Wk[a][j], split to bf16 hi/lo.
__global__ void cca_compute_M(const float* __restrict__ Wq,
                              const float* __restrict__ Wk,
                              short* __restrict__ MTh, short* __restrict__ MTl) {
  __shared__ float Wqs[64 * 17];
  __shared__ float Wks[64 * 17];
  const int tid = threadIdx.x;
  const int ti = tid >> 4;
  const int tj = tid & 15;  // consecutive lanes -> i (coalesced MT write)
  const int i0 = (blockIdx.x & 31) << 4;
  const int j0 = (blockIdx.x >> 5) << 4;
  float acc = 0.f;
  for (int ac = 0; ac < 8; ++ac) {
    __syncthreads();
#pragma unroll
    for (int s = 0; s < 4; ++s) {
      int idx = tid + 256 * s;
      int r = idx >> 4;
      int c = idx & 15;
      Wqs[r * 17 + c] = Wq[(ac * 64 + r) * 512 + i0 + c];
      Wks[r * 17 + c] = Wk[(ac * 64 + r) * 512 + j0 + c];
    }
    __syncthreads();
#pragma unroll
    for (int r = 0; r < 64; ++r)
      acc = fmaf(Wqs[r * 17 + tj], Wks[r * 17 + ti], acc);  // i=i0+tj, j=j0+ti
  }
  short hb = f2bf(acc);
  MTh[(j0 + ti) * 512 + i0 + tj] = hb;
  MTl[(j0 + ti) * 512 + i0 + tj] = f2bf(acc - bf2f(hb));
}

__global__ __launch_bounds__(256, 2) void cca_fused(
    const float* __restrict__ x, const float* __restrict__ Wv,
    const short* __restrict__ MTh_g, const short* __restrict__ MTl_g,
    const float* __restrict__ gammaP, float* __restrict__ out) {
  // 64 KB arena, phase-unioned:
  //  Phase A : Xh[128][64]@0  Xl@16384 | MThs[64][64]@32768 MTls@40960 (k-loop)
  //            Th[128][64]@32768 Tl@49152 (overlay MT after barrier)
  //  Phase B : attn[128][128]@32768 (overlay T) | Xb@0 Wvb@16384 (stage)
  //            Vt[128][128]@0 (overlay stage after barrier)
  __shared__ __align__(16) char smem[65536];
  char* Xh = smem;
  char* Xl = smem + 16384;
  char* MThs = smem + 32768;
  char* MTls = smem + 40960;
  char* Th = smem + 32768;
  char* Tl = smem + 49152;
  char* attnS = smem + 32768;
  char* Xb = smem;
  char* Wvb = smem + 16384;
  char* Vt = smem;

  const int tid = threadIdx.x;
  const int w4 = tid >> 6;   // wave 0..3
  const int lane = tid & 63;
  const int lq = lane >> 4;  // 0..3
  const int lr = lane & 15;  // 0..15
  const int col = blockIdx.x;
  const int bb = col >> 7;
  const int wcol = col & 127;
  const float* xcol = x + ((size_t)bb * (HH * WW) + wcol) * CS;
  float* ocol = out + ((size_t)bb * (HH * WW) + wcol) * CS;

  // E^T accumulators: D[g][h], wave w owns h-cols [32w,32w+32).
  // lane: g = 16*rt + 4*lq + r, h = 32*w4 + 16*ct + lr
  f32x4 et[8][2];
#pragma unroll
  for (int rt = 0; rt < 8; ++rt)
#pragma unroll
    for (int ct = 0; ct < 2; ++ct) et[rt][ct] = (f32x4){0.f, 0.f, 0.f, 0.f};

  // ---------------- Phase A: E^T = Xj @ T^T per 64-wide j window ----------------
  for (int j8 = 0; j8 < 8; ++j8) {
    // GEMM1: Tt[j][h] = sum_c MT[j][c] * x[h][c]  (D[j][h], wave owns h-cols)
    f32x4 tt[4][2];
#pragma unroll
    for (int jt = 0; jt < 4; ++jt)
#pragma unroll
      for (int ct = 0; ct < 2; ++ct) tt[jt][ct] = (f32x4){0.f, 0.f, 0.f, 0.f};

    for (int kk = 1; kk <= 8; ++kk) {
      int kc = (j8 + kk) & 7;  // ends at kc == j8 -> X arena then holds Xj
      __syncthreads();         // protect X/MT (and prior j8's T readers)
      stage_hilo(xcol + kc * 64, HSTRIDE, Xh, Xl, tid);
      stage_mt(MTh_g + (size_t)(j8 * 64) * 512 + kc * 64, MThs, tid);
      stage_mt(MTl_g + (size_t)(j8 * 64) * 512 + kc * 64, MTls, tid);
      __syncthreads();
#pragma unroll
      for (int ks = 0; ks < 2; ++ks) {
        bf16x8 ah[4], al[4], bh[2], bl[2];
#pragma unroll
        for (int jt = 0; jt < 4; ++jt) {
          ah[jt] = frag64(MThs, 16 * jt + lr, ks, lq);
          al[jt] = frag64(MTls, 16 * jt + lr, ks, lq);
        }
#pragma unroll
        for (int ct = 0; ct < 2; ++ct) {
          int hrow = 32 * w4 + 16 * ct + lr;
          bh[ct] = frag64(Xh, hrow, ks, lq);
          bl[ct] = frag64(Xl, hrow, ks, lq);
        }
#pragma unroll
        for (int jt = 0; jt < 4; ++jt)
#pragma unroll
          for (int ct = 0; ct < 2; ++ct) {
            tt[jt][ct] = MFMA(ah[jt], bh[ct], tt[jt][ct]);
            tt[jt][ct] = MFMA(ah[jt], bl[ct], tt[jt][ct]);
            tt[jt][ct] = MFMA(al[jt], bh[ct], tt[jt][ct]);
          }
      }
    }
    __syncthreads();  // all waves done reading MT region -> overlay T
    // T write: lane holds col h fixed, 4 consecutive j -> contiguous b64 packs
#pragma unroll
    for (int jt = 0; jt < 4; ++jt)
#pragma unroll
      for (int ct = 0; ct < 2; ++ct) {
        int hrow = 32 * w4 + 16 * ct + lr;
        int jb = 16 * jt + 4 * lq;
        s4v h, l;
#pragma unroll
        for (int r = 0; r < 4; ++r) {
          float f = tt[jt][ct][r];
          short hb = f2bf(f);
          h[r] = hb;
          l[r] = f2bf(f - bf2f(hb));
        }
        st64(Th, hrow, jb, h);
        st64(Tl, hrow, jb, l);
      }
    // GEMM2': Et[g][h] += sum_j Xj[g][j] * T[h][j].
    // B-frags read only this wave's own T rows (no barrier needed); Xj is the
    // kc==j8 stage, stable since its barrier.
#pragma unroll
    for (int ks = 0; ks < 2; ++ks) {
      bf16x8 axh[8], axl[8], bth[2], btl[2];
#pragma unroll
      for (int rt = 0; rt < 8; ++rt) {
        axh[rt] = frag64(Xh, 16 * rt + lr, ks, lq);
        axl[rt] = frag64(Xl, 16 * rt + lr, ks, lq);
      }
#pragma unroll
      for (int ct = 0; ct < 2; ++ct) {
        int hrow = 32 * w4 + 16 * ct + lr;
        bth[ct] = frag64(Th, hrow, ks, lq);
        btl[ct] = frag64(Tl, hrow, ks, lq);
      }
#pragma unroll
      for (int rt = 0; rt < 8; ++rt)
#pragma unroll
        for (int ct = 0; ct < 2; ++ct) {
          et[rt][ct] = MFMA(axh[rt], bth[ct], et[rt][ct]);
          et[rt][ct] = MFMA(axh[rt], btl[ct], et[rt][ct]);
          et[rt][ct] = MFMA(axl[rt], bth[ct], et[rt][ct]);
        }
    }
  }

  // ---------------- masked softmax over g (rows of Et), fp32 in regs ----------------
#pragma unroll
  for (int rt = 0; rt < 8; ++rt)
#pragma unroll
    for (int ct = 0; ct < 2; ++ct)
#pragma unroll
      for (int r = 0; r < 4; ++r) {
        int g = 16 * rt + 4 * lq + r;
        int h = 32 * w4 + 16 * ct + lr;
        if (g == h) et[rt][ct][r] = -INFINITY;  // diagonal mask
      }
  float inv[2];
#pragma unroll
  for (int ct = 0; ct < 2; ++ct) {
    float mx = -INFINITY;
#pragma unroll
    for (int rt = 0; rt < 8; ++rt)
#pragma unroll
      for (int r = 0; r < 4; ++r) mx = fmaxf(mx, et[rt][ct][r]);
    mx = fmaxf(mx, __shfl_xor(mx, 16, 64));  // lanes sharing h differ in bits 4,5
    mx = fmaxf(mx, __shfl_xor(mx, 32, 64));
    float s = 0.f;
#pragma unroll
    for (int rt = 0; rt < 8; ++rt)
#pragma unroll
      for (int r = 0; r < 4; ++r) {
        float p = __expf(et[rt][ct][r] - mx);
        et[rt][ct][r] = p;
        s += p;
      }
    s += __shfl_xor(s, 16, 64);
    s += __shfl_xor(s, 32, 64);
    inv[ct] = 1.f / s;
  }
  __syncthreads();  // T region readers done everywhere -> overlay attn
#pragma unroll
  for (int rt = 0; rt < 8; ++rt)
#pragma unroll
    for (int ct = 0; ct < 2; ++ct) {
      int h = 32 * w4 + 16 * ct + lr;
      int gb = 16 * rt + 4 * lq;
      s4v p;
#pragma unroll
      for (int r = 0; r < 4; ++r) p[r] = f2bf(et[rt][ct][r] * inv[ct]);
      st128(attnS, h, gb, p);  // attn[h][g], own-wave rows for GEMM4
    }

  // -------- Phase B: Vt = (x@Wv^T)^T per 128-wide m window; O = attn@V --------
  const float gmm = gammaP[0];
  for (int mc = 0; mc < 4; ++mc) {
    // GEMM3: V[g][m] = sum_c x[g][c]*Wv[m][c]  (D[g][m], wave owns g-rows)
    f32x4 vv[2][8];
#pragma unroll
    for (int rt = 0; rt < 2; ++rt)
#pragma unroll
      for (int ct = 0; ct < 8; ++ct) vv[rt][ct] = (f32x4){0.f, 0.f, 0.f, 0.f};
    for (int kc = 0; kc < 8; ++kc) {
      __syncthreads();  // protect stage region (prev GEMM3 / prev mc's Vt readers)
      stage_hi(xcol + kc * 64, HSTRIDE, Xb, tid);
      stage_hi(Wv + (size_t)(mc * 128) * 512 + kc * 64, 512, Wvb, tid);
      __syncthreads();
#pragma unroll
      for (int ks = 0; ks < 2; ++ks) {
        bf16x8 ax[2], bw[8];
#pragma unroll
        for (int rt = 0; rt < 2; ++rt) ax[rt] = frag64(Xb, 32 * w4 + 16 * rt + lr, ks, lq);
#pragma unroll
        for (int ct = 0; ct < 8; ++ct) bw[ct] = frag64(Wvb, 16 * ct + lr, ks, lq);
#pragma unroll
        for (int rt = 0; rt < 2; ++rt)
#pragma unroll
          for (int ct = 0; ct < 8; ++ct) vv[rt][ct] = MFMA(ax[rt], bw[ct], vv[rt][ct]);
      }
    }
    __syncthreads();  // stage reads done -> overlay Vt
    // Vt write: lane holds col m fixed, 4 consecutive g -> contiguous packs
#pragma unroll
    for (int rt = 0; rt < 2; ++rt)
#pragma unroll
      for (int ct = 0; ct < 8; ++ct) {
        int m = 16 * ct + lr;
        int gb = 32 * w4 + 16 * rt + 4 * lq;
        s4v h;
#pragma unroll
        for (int r = 0; r < 4; ++r) h[r] = f2bf(vv[rt][ct][r]);
        st128(Vt, m, gb, h);
      }
    __syncthreads();  // Vt is cross-wave for GEMM4
    // GEMM4: O[h][m] = sum_g attn[h][g] * Vt[m][g]
    f32x4 oo[2][8];
#pragma unroll
    for (int rt = 0; rt < 2; ++rt)
#pragma unroll
      for (int ct = 0; ct < 8; ++ct) oo[rt][ct] = (f32x4){0.f, 0.f, 0.f, 0.f};
#pragma unroll
    for (int ks = 0; ks < 4; ++ks) {
      bf16x8 aa[2], bv[8];
#pragma unroll
      for (int rt = 0; rt < 2; ++rt) aa[rt] = frag128(attnS, 32 * w4 + 16 * rt + lr, ks, lq);
#pragma unroll
      for (int ct = 0; ct < 8; ++ct) bv[ct] = frag128(Vt, 16 * ct + lr, ks, lq);
#pragma unroll
      for (int rt = 0; rt < 2; ++rt)
#pragma unroll
        for (int ct = 0; ct < 8; ++ct) oo[rt][ct] = MFMA(aa[rt], bv[ct], oo[rt][ct]);
    }
    // epilogue: out = gamma*O + x ; lanes lr=0..15 give 64-B contiguous segments
#pragma unroll
    for (int rt = 0; rt < 2; ++rt)
#pragma unroll
      for (int r = 0; r < 4; ++r) {
        int h = 32 * w4 + 16 * rt + 4 * lq + r;
        const float* xr = xcol + (size_t)h * HSTRIDE + mc * 128;
        float* orow = ocol + (size_t)h * HSTRIDE + mc * 128;
#pragma unroll
        for (int ct = 0; ct < 8; ++ct) {
          int cg = 16 * ct + lr;
          orow[cg] = fmaf(gmm, oo[rt][ct][r], xr[cg]);
        }
      }
  }
}

extern "C" void kernel_launch(void* const* d_in, const int* in_sizes, int n_in,
                              void* d_out, int out_size, void* d_ws, size_t ws_size,
                              hipStream_t stream) {
  const float* x = (const float*)d_in[0];
  const float* Wq = (const float*)d_in[1];
  const float* Wk = (const float*)d_in[2];
  const float* Wv = (const float*)d_in[3];
  const float* gamma = (const float*)d_in[4];
  float* out = (float*)d_out;
  short* MTh = (short*)d_ws;                          // 512*512*2 B
  short* MTl = (short*)((char*)d_ws + 512 * 512 * 2); // 1 MB total ws

  cca_compute_M<<<1024, 256, 0, stream>>>(Wq, Wk, MTh, MTl);
  cca_fused<<<1024, 256, 0, stream>>>(x, Wv, MTh, MTl, gamma, out);
}